// Round 7
// baseline (428.585 us; speedup 1.0000x reference)
//
#include <hip/hip_runtime.h>

#define B_DIM 2048
#define IN_DIM 1024
#define M_DIM 256
#define P_DIM 32896            // 256*257/2
#define NPAD 33024             // 129 panels of 256
#define RTP_B 40960            // elements per batch: row-tile padded, chunk-XOR swizzled
#define CRTP_BYTES (167772160) // 2048*40960*2
#define WB_BYTES   (67633152)  // 33024*1024*2 (incl. 128 zero pad rows)

typedef __attribute__((ext_vector_type(8))) short short8;
typedef __attribute__((ext_vector_type(4))) float f32x4;

#define GLD16(gsrc, ldst) __builtin_amdgcn_global_load_lds(                    \
    (const __attribute__((address_space(1))) unsigned int*)(gsrc),             \
    (__attribute__((address_space(3))) unsigned int*)(ldst), 16, 0, 0)

__device__ __forceinline__ unsigned short f2bf(float f) {
    unsigned int u = __float_as_uint(f);
    u += 0x7FFFu + ((u >> 16) & 1u);          // RNE to bf16
    return (unsigned short)(u >> 16);
}
// base offset of row r: tile g padded to (g+1)*64 cols (rows 128B-aligned)
__device__ __forceinline__ int rtp0(int r) {
    const int g = r >> 6;
    return 2048 * g * (g + 1) + (r & 63) * ((g + 1) << 6);
}
// element (r,c): 8-el chunk index XOR'd by (r&7)
__device__ __forceinline__ int rtp_off(int r, int c) {
    return rtp0(r) + (((c >> 3) ^ (r & 7)) << 3) + (c & 7);
}

// ---------------- merged prep: W cvt | X cvt | Wb pad zero | Crtp pad zero ----------
#define NW_BLK 8224            // 8224*1024 float4 = 32896*1024/4
#define NX_BLK 512             // 512*1024  float4 = 2048*1024/4
#define NP_BLK 16              // Wb pad: 16*8192 els = 131072 = 128 rows
#define NZ_BLK 2048
__global__ void prep_all(const float* __restrict__ X, const float* __restrict__ W,
                         unsigned short* __restrict__ Xhi, unsigned short* __restrict__ Wb,
                         unsigned short* __restrict__ Crtp) {
    const int bid = blockIdx.x, tid = threadIdx.x;
    if (bid < NW_BLK) {
#pragma unroll
        for (int u = 0; u < 4; ++u) {
            const int i = bid * 1024 + u * 256 + tid;
            float4 v = reinterpret_cast<const float4*>(W)[i];
            ushort4 h;
            h.x = f2bf(v.x); h.y = f2bf(v.y); h.z = f2bf(v.z); h.w = f2bf(v.w);
            reinterpret_cast<ushort4*>(Wb)[i] = h;
        }
    } else if (bid < NW_BLK + NX_BLK) {
#pragma unroll
        for (int u = 0; u < 4; ++u) {
            const int i = (bid - NW_BLK) * 1024 + u * 256 + tid;
            float4 v = reinterpret_cast<const float4*>(X)[i];
            ushort4 h;
            h.x = f2bf(v.x); h.y = f2bf(v.y); h.z = f2bf(v.z); h.w = f2bf(v.w);
            reinterpret_cast<ushort4*>(Xhi)[i] = h;
        }
    } else if (bid < NW_BLK + NX_BLK + NP_BLK) {
        uint4* dst = reinterpret_cast<uint4*>(Wb + (size_t)P_DIM * IN_DIM);
        const uint4 z = make_uint4(0u, 0u, 0u, 0u);
#pragma unroll
        for (int u = 0; u < 4; ++u)
            dst[((bid - NW_BLK - NX_BLK) * 256 + tid) * 4 + u] = z;
    } else {
        const int b = bid - NW_BLK - NX_BLK - NP_BLK;   // batch
        const int r = tid;                               // row
        const int g = r >> 6;
        const int nch = (g + 1) << 3;
        const int xm = r & 7;
        unsigned short* base = Crtp + (size_t)b * RTP_B + rtp0(r);
        const int pc = (r >> 3) ^ xm;
        for (int c = r + 1; (c >> 3) == (r >> 3); ++c) base[(pc << 3) + (c & 7)] = 0;
        const uint4 z = make_uint4(0u, 0u, 0u, 0u);
        for (int cc = (r >> 3) + 1; cc < nch; ++cc)
            *reinterpret_cast<uint4*>(&base[(cc ^ xm) << 3]) = z;
    }
}

// ---------------- Stage 1: C = Xhi @ Wb^T + bias, diag-ReLU, store rtp bf16 ----------
// BM=256, BN=256, BK=32. 512 threads = 8 waves (4M x 2N), wave tile 64x128.
// Triple-buffered LDS (3 x 32KB), prefetch depth 2, counted vmcnt(4), 1 barrier/iter.
// Grid 1032 = 8 XCDs x 129 panels; XCD x owns row-tile x (X slice 0.5 MB, L2-resident);
// all XCDs walk panel j together -> W panel fetched from HBM ~once (L3-shared).
__global__ __launch_bounds__(512) void gemm1_kernel(
    const unsigned short* __restrict__ Xhi,
    const unsigned short* __restrict__ Wb, const float* __restrict__ bias,
    unsigned short* __restrict__ Crtp)
{
    __shared__ unsigned short lds[3 * 16384];      // per buf: A 8192 els | B 8192 els

    const int lin = blockIdx.x;
    const int row0 = (lin & 7) << 8;               // XCD -> row-tile
    const int col0 = (lin >> 3) << 8;              // panel (0..128)

    const int tid  = threadIdx.x;
    const int lane = tid & 63;
    const int wid  = tid >> 6;                     // 0..7
    const int wr   = wid & 3;                      // 4 M-waves
    const int wc   = wid >> 2;                     // 2 N-waves
    const int lr16 = lane & 15;
    const int kc   = lane >> 4;

    // staging: per K-tile each wave issues 2 GLD16 for A rows [wid*32,+32) + 2 for B.
    // lane -> row lane>>2, chunk lane&3; source chunk pre-XOR'd by xk(row)=(row>>1)&3.
    const int srow = lane >> 2;                    // 0..15
    const int sch  = (lane & 3) ^ ((lane >> 3) & 3);
    const unsigned short* gA = Xhi + (size_t)(row0 + wid * 32 + srow) * IN_DIM + (sch << 3);
    const unsigned short* gB = Wb  + (size_t)(col0 + wid * 32 + srow) * IN_DIM + (sch << 3);
    const int la = (wid * 32) * 32;                // LDS el offset of wave's A rows
    const int lb = 8192 + (wid * 32) * 32;

#define STAGE(kt, bufo)                                                        \
    {                                                                          \
        GLD16(gA + (kt) * 32,                 &lds[(bufo) + la]);              \
        GLD16(gA + 16 * IN_DIM + (kt) * 32,   &lds[(bufo) + la + 512]);        \
        GLD16(gB + (kt) * 32,                 &lds[(bufo) + lb]);              \
        GLD16(gB + 16 * IN_DIM + (kt) * 32,   &lds[(bufo) + lb + 512]);        \
    }

    f32x4 acc[4][8];
#pragma unroll
    for (int m = 0; m < 4; ++m)
#pragma unroll
        for (int n = 0; n < 8; ++n) acc[m][n] = (f32x4){0.f, 0.f, 0.f, 0.f};

    int o0 = 0, o1 = 16384, o2 = 32768;
    STAGE(0, o0);
    STAGE(1, o1);

    for (int it = 0; it < 32; ++it) {
        if (it < 31) asm volatile("s_waitcnt vmcnt(4)" ::: "memory");
        else         asm volatile("s_waitcnt vmcnt(0)" ::: "memory");
        __builtin_amdgcn_s_barrier();
        asm volatile("" ::: "memory");             // keep ds_reads below the barrier

        const int cb = o0;
        short8 av[4], bv[8];
#pragma unroll
        for (int m = 0; m < 4; ++m) {
            const int r = (wr << 6) + (m << 4) + lr16;
            av[m] = *reinterpret_cast<const short8*>(
                &lds[cb + r * 32 + ((kc ^ ((r >> 1) & 3)) << 3)]);
        }
#pragma unroll
        for (int n = 0; n < 8; ++n) {
            const int r = (wc << 7) + (n << 4) + lr16;
            bv[n] = *reinterpret_cast<const short8*>(
                &lds[cb + 8192 + r * 32 + ((kc ^ ((r >> 1) & 3)) << 3)]);
        }
        if (it < 30) STAGE(it + 2, o2);            // prefetch depth 2
        __builtin_amdgcn_s_setprio(1);
#pragma unroll
        for (int m = 0; m < 4; ++m)
#pragma unroll
            for (int n = 0; n < 8; ++n)
                acc[m][n] = __builtin_amdgcn_mfma_f32_16x16x32_bf16(av[m], bv[n], acc[m][n], 0, 0, 0);
        __builtin_amdgcn_s_setprio(0);

        const int t = o0; o0 = o1; o1 = o2; o2 = t;   // rotate ring
    }
#undef STAGE

    // epilogue: D col = lane&15, row = (lane>>4)*4 + reg
#pragma unroll
    for (int n = 0; n < 8; ++n) {
        const int p = col0 + (wc << 7) + (n << 4) + lr16;     // packed tril index
        if (p >= P_DIM) continue;                             // pad panel guard
        const float t = sqrtf((float)(8 * p + 1));
        const int rt = (int)((t - 1.0f) * 0.5f + 0.001f);     // tril row
        const int ct = p - ((rt * (rt + 1)) >> 1);            // tril col
        const int off = rtp_off(rt, ct);                      // swizzled position
        const bool diag = (ct == rt);
        const float bvs = bias[p];
#pragma unroll
        for (int m = 0; m < 4; ++m) {
#pragma unroll
            for (int q = 0; q < 4; ++q) {
                const int brow = row0 + (wr << 6) + (m << 4) + (kc << 2) + q;
                float v = acc[m][n][q] + bvs;
                if (diag) v = fmaxf(v, 0.f);
                Crtp[(size_t)brow * RTP_B + off] = f2bf(v);
            }
        }
    }
}

// ---------------- Stage 2: O[b] = L_b @ L_b^T, LDS-staged (80 KB -> 2 blocks/CU) ------
__global__ __launch_bounds__(256) void syrk_kernel(
    const unsigned short* __restrict__ Crtp, float* __restrict__ O)
{
    __shared__ unsigned short Lt[RTP_B];       // 81920 B exactly -> 2 blocks/CU
    const int tid  = threadIdx.x;
    const int lane = tid & 63;
    const int wid  = tid >> 6;
    const int b    = blockIdx.x;
    const unsigned short* Cb = Crtp + (size_t)b * RTP_B;

#pragma unroll
    for (int i = 0; i < 20; ++i) {
        const int g = wid * 20 + i;
        GLD16(Cb + g * 512 + (lane << 3), &Lt[g * 512]);
    }
    __syncthreads();

    const int lr16 = lane & 15;
    const int kc   = lane >> 4;
    float* Ob = O + (size_t)b * (M_DIM * M_DIM);

    const unsigned char LIST[4][5] = {
        {0x33, 0x22, 0x00, 0x00, 0x00},
        {0x23, 0x32, 0x01, 0x10, 0x00},
        {0x11, 0x12, 0x21, 0x02, 0x00},
        {0x13, 0x31, 0x03, 0x30, 0x20}};
    const int CNT[4] = {3, 4, 4, 5};
    const int cnt = CNT[wid];

    for (int tt = 0; tt < cnt; ++tt) {
        const int code = LIST[wid][tt];
        const int ti = code >> 4, tj = code & 15;

        int baseA[4], xA[4], baseB[4], xB[4];
#pragma unroll
        for (int m = 0; m < 4; ++m) {
            const int ia = (ti << 6) + (m << 4) + lr16;
            const int jb = (tj << 6) + (m << 4) + lr16;
            baseA[m] = rtp0(ia); xA[m] = ia & 7;
            baseB[m] = rtp0(jb); xB[m] = jb & 7;
        }
        f32x4 acc[4][4];
#pragma unroll
        for (int m = 0; m < 4; ++m)
#pragma unroll
            for (int n = 0; n < 4; ++n) acc[m][n] = (f32x4){0.f, 0.f, 0.f, 0.f};

        const int kmax = ti < tj ? ti : tj;
        for (int kt = 0; kt <= kmax; ++kt) {
#pragma unroll
            for (int s = 0; s < 2; ++s) {
                const int cidx = (kt << 3) + (s << 2) + kc;   // 8-el chunk index
                short8 a[4], bb[4];
#pragma unroll
                for (int m = 0; m < 4; ++m)
                    a[m] = *reinterpret_cast<const short8*>(&Lt[baseA[m] + ((cidx ^ xA[m]) << 3)]);
#pragma unroll
                for (int n = 0; n < 4; ++n)
                    bb[n] = *reinterpret_cast<const short8*>(&Lt[baseB[n] + ((cidx ^ xB[n]) << 3)]);
#pragma unroll
                for (int m = 0; m < 4; ++m)
#pragma unroll
                    for (int n = 0; n < 4; ++n)
                        acc[m][n] = __builtin_amdgcn_mfma_f32_16x16x32_bf16(a[m], bb[n], acc[m][n], 0, 0, 0);
            }
        }
#pragma unroll
        for (int m = 0; m < 4; ++m) {
            const int i0 = (ti << 6) + (m << 4) + (kc << 2);
#pragma unroll
            for (int n = 0; n < 4; ++n) {
                const int j = (tj << 6) + (n << 4) + lr16;
#pragma unroll
                for (int q = 0; q < 4; ++q)
                    __builtin_nontemporal_store(acc[m][n][q], &Ob[(size_t)(i0 + q) * M_DIM + j]);
            }
        }
    }
}

extern "C" void kernel_launch(void* const* d_in, const int* in_sizes, int n_in,
                              void* d_out, int out_size, void* d_ws, size_t ws_size,
                              hipStream_t stream)
{
    (void)in_sizes; (void)n_in; (void)out_size; (void)ws_size;
    const float* x    = (const float*)d_in[0];
    const float* W    = (const float*)d_in[1];
    const float* bias = (const float*)d_in[2];
    float* O = (float*)d_out;

    char* ws = (char*)d_ws;
    unsigned short* Crtp = (unsigned short*)ws;
    unsigned short* Wb   = (unsigned short*)(ws + CRTP_BYTES);
    unsigned short* Xhi  = (unsigned short*)(ws + CRTP_BYTES + WB_BYTES);

    prep_all<<<dim3(NW_BLK + NX_BLK + NP_BLK + NZ_BLK), dim3(256), 0, stream>>>(
        x, W, Xhi, Wb, Crtp);
    gemm1_kernel<<<dim3(1032), dim3(512), 0, stream>>>(Xhi, Wb, bias, Crtp);
    syrk_kernel<<<dim3(B_DIM), dim3(256), 0, stream>>>(Crtp, O);
}